// Round 2
// baseline (240.806 us; speedup 1.0000x reference)
//
#include <hip/hip_runtime.h>

#define B_ 8
#define N_ 1024
#define D_ 768
#define H_ 12
#define HD_ 64

typedef __attribute__((ext_vector_type(8))) short bf16x8;
typedef __attribute__((ext_vector_type(4))) short short4_t;
typedef __attribute__((ext_vector_type(4))) float f32x4;
typedef unsigned int u32;

__device__ __forceinline__ short f2bf(float f) {
  union { float f; unsigned u; } v; v.f = f;
  unsigned u = v.u;
  unsigned r = u + 0x7fffu + ((u >> 16) & 1u);
  return (short)(r >> 16);
}
__device__ __forceinline__ float bf2f(short s) {
  union { unsigned u; float f; } v;
  v.u = ((unsigned)(unsigned short)s) << 16;
  return v.f;
}

// direct global -> LDS DMA, 16B per lane. LDS dest = wave-uniform base + lane*16.
__device__ __forceinline__ void gload_lds16(const void* g, void* l) {
  __builtin_amdgcn_global_load_lds((const __attribute__((address_space(1))) u32*)g,
                                   (__attribute__((address_space(3))) u32*)l, 16, 0, 0);
}

// ---------------- conversion: X f32 -> bf16 ----------------
__global__ void cvt_x_kernel(const float* __restrict__ X, short* __restrict__ Xb) {
  int i = (blockIdx.x * 256 + threadIdx.x) * 8;
  float4 a = *(const float4*)(X + i);
  float4 b = *(const float4*)(X + i + 4);
  bf16x8 o;
  o[0] = f2bf(a.x); o[1] = f2bf(a.y); o[2] = f2bf(a.z); o[3] = f2bf(a.w);
  o[4] = f2bf(b.x); o[5] = f2bf(b.y); o[6] = f2bf(b.z); o[7] = f2bf(b.w);
  *(bf16x8*)(Xb + i) = o;
}

// ---------------- conversion: W f32 -> bf16, transposed (Wt[n][k] = W[k][n]) ----------------
__global__ void cvt_w_kernel(const float* __restrict__ Wq, const float* __restrict__ Wk,
                             const float* __restrict__ Wv, short* __restrict__ Wt3) {
  const float* W = blockIdx.z == 0 ? Wq : (blockIdx.z == 1 ? Wk : Wv);
  short* O = Wt3 + (size_t)blockIdx.z * D_ * D_;
  __shared__ float t[32][33];
  int n0 = blockIdx.x * 32, k0 = blockIdx.y * 32;
  int tx = threadIdx.x, ty = threadIdx.y;
#pragma unroll
  for (int j = 0; j < 4; j++)
    t[ty + 8 * j][tx] = W[(size_t)(k0 + ty + 8 * j) * D_ + n0 + tx];
  __syncthreads();
#pragma unroll
  for (int j = 0; j < 4; j++)
    O[(size_t)(n0 + ty + 8 * j) * D_ + k0 + tx] = f2bf(t[tx][ty + 8 * j]);
}

// ---------------- QKV projection GEMM: C = X @ W + b (bf16 out, Q pre-scaled by 0.125) ----------------
__global__ __launch_bounds__(256, 4)
void qkv_gemm_kernel(const short* __restrict__ Xb, const short* __restrict__ Wt3,
                     const float* __restrict__ bq, const float* __restrict__ bk,
                     const float* __restrict__ bv, short* __restrict__ QKV) {
  const int z = blockIdx.z;
  const short* Wt = Wt3 + (size_t)z * D_ * D_;
  const float* bias = z == 0 ? bq : (z == 1 ? bk : bv);
  short* C = QKV + (size_t)z * (B_ * N_) * D_;
  const float alpha = (z == 0) ? 0.125f : 1.0f;

  const int m0 = blockIdx.x * 128;
  const int n0 = blockIdx.y * 128;
  const int tid = threadIdx.x;
  const int lane = tid & 63;
  const int wid = tid >> 6;
  const int wr = (wid >> 1) * 64;
  const int wc = (wid & 1) * 64;
  const int l15 = lane & 15;
  const int lg = lane >> 4;

  // unpadded, XOR-swizzled: row r phys chunk p (16B) holds logical chunk p^(r&3)
  __shared__ short At[128][32];
  __shared__ short Bt[128][32];

  f32x4 acc[4][4];
#pragma unroll
  for (int m = 0; m < 4; m++)
#pragma unroll
    for (int n = 0; n < 4; n++)
      acc[m][n] = (f32x4){0.f, 0.f, 0.f, 0.f};

  // DMA source mapping: lane -> row (wid+4p)*16 + (lane>>2), phys chunk lane&3,
  // logical chunk (lane&3)^(row&3) = (lane&3)^((lane>>2)&3)
  const int srow_l = lane >> 2;
  const int sc8 = (((lane & 3) ^ ((lane >> 2) & 3)) * 8);

  for (int k0 = 0; k0 < D_; k0 += 32) {
    __syncthreads();
#pragma unroll
    for (int p = 0; p < 2; p++) {
      const int row = (wid + 4 * p) * 16 + srow_l;
      gload_lds16(Xb + (size_t)(m0 + row) * D_ + k0 + sc8,
                  ((short*)At) + (size_t)(wid + 4 * p) * 512);
      gload_lds16(Wt + (size_t)(n0 + row) * D_ + k0 + sc8,
                  ((short*)Bt) + (size_t)(wid + 4 * p) * 512);
    }
    __syncthreads();

    bf16x8 af[4], bfr[4];
#pragma unroll
    for (int m = 0; m < 4; m++) {
      const int row = wr + m * 16 + l15;
      af[m] = *(const bf16x8*)&At[row][(lg ^ (l15 & 3)) * 8];
    }
#pragma unroll
    for (int n = 0; n < 4; n++) {
      const int row = wc + n * 16 + l15;
      bfr[n] = *(const bf16x8*)&Bt[row][(lg ^ (l15 & 3)) * 8];
    }
#pragma unroll
    for (int m = 0; m < 4; m++)
#pragma unroll
      for (int n = 0; n < 4; n++)
        acc[m][n] = __builtin_amdgcn_mfma_f32_16x16x32_bf16(af[m], bfr[n], acc[m][n], 0, 0, 0);
  }

#pragma unroll
  for (int n = 0; n < 4; n++) {
    const int col = n0 + wc + n * 16 + l15;
    const float bval = bias[col];
#pragma unroll
    for (int m = 0; m < 4; m++) {
#pragma unroll
      for (int r = 0; r < 4; r++) {
        const int row = m0 + wr + m * 16 + 4 * lg + r;
        C[(size_t)row * D_ + col] = f2bf((acc[m][n][r] + bval) * alpha);
      }
    }
  }
}

// ---------------- flash-style masked attention ----------------
__global__ __launch_bounds__(256, 5)
void attn_kernel(const short* __restrict__ QKV, const float* __restrict__ adj,
                 const float* __restrict__ beta_p, float* __restrict__ out) {
  const short* Qb = QKV;
  const short* Kb = QKV + (size_t)(B_ * N_) * D_;
  const short* Vb = QKV + 2 * (size_t)(B_ * N_) * D_;

  const int qt = blockIdx.x;   // 0..15  q tile
  const int h  = blockIdx.y;   // 0..11  head
  const int b  = blockIdx.z;   // 0..7   batch
  const int tid = threadIdx.x;
  const int lane = tid & 63;
  const int w = tid >> 6;      // wave 0..3: q rows [16w,16w+16)
  const int l15 = lane & 15;
  const int lg = lane >> 4;

  const float beta = beta_p[0];
  const int q0 = qt * 64;
  const size_t seq0 = (size_t)b * N_;
  const int hc = h * HD_;

  // Kt: row k', phys chunk p holds K[k'][ (p^(k'&7))*8 .. +8 )   (linear for DMA)
  __shared__ short Kt[64][64];
  // VT: transposed V, VT[d][ k ^ (((d&7)^((d>>3)&7))<<3) ] = V[k][d]
  __shared__ short VT[64][64];
  __shared__ short Pt[4][16][72];

  bf16x8 qf[2];
  {
    const short* qp = Qb + (seq0 + q0 + 16 * w + l15) * (size_t)D_ + hc + 8 * lg;
    qf[0] = *(const bf16x8*)qp;
    qf[1] = *(const bf16x8*)(qp + 32);
  }

  f32x4 acc[4];
#pragma unroll
  for (int cb = 0; cb < 4; cb++) acc[cb] = (f32x4){0.f, 0.f, 0.f, 0.f};
  float mrow[4], lrow[4];
#pragma unroll
  for (int r = 0; r < 4; r++) { mrow[r] = -__builtin_inff(); lrow[r] = 0.f; }

  const float* adj_base = adj + ((size_t)b * N_ + q0 + 16 * w + 4 * lg) * (size_t)N_ + l15;

  // K DMA mapping (per wave): lane -> row w*16 + pass*8 + (lane>>3), phys chunk lane&7,
  // logical chunk (lane&7)^(row&7) = (lane&7)^(lane>>3)
  const int krow = 16 * w + (lane >> 3);
  const int kc8 = ((lane & 7) ^ (lane >> 3)) * 8;
  // V staging: thread reads V[rr][scol..scol+7], scatters to VT
  const int srow = tid >> 3;        // 0..31
  const int scol = (tid & 7) * 8;   // 0..56
  const int fv_t = (tid & 7);       // (d>>3)&7 for this thread's d-range

  for (int kt = 0; kt < 16; kt++) {
    const int k0 = kt * 64;
    __syncthreads();

    // --- K: direct global->LDS DMA (2 x 16 rows per wave) ---
    {
      const short* g0 = Kb + (seq0 + k0 + krow) * (size_t)D_ + hc + kc8;
      gload_lds16(g0, ((short*)Kt) + (size_t)w * 1024);
      const short* g1 = g0 + 8 * (size_t)D_;
      gload_lds16(g1, ((short*)Kt) + (size_t)w * 1024 + 512);
    }

    // --- V: reg-stage + transposed swizzled scatter ---
    bf16x8 v0 = *(const bf16x8*)(Vb + (seq0 + k0 + srow) * (size_t)D_ + hc + scol);
    bf16x8 v1 = *(const bf16x8*)(Vb + (seq0 + k0 + srow + 32) * (size_t)D_ + hc + scol);

    // --- adj prefetch (latency hides under staging + MFMA) ---
    float av[4][4];
#pragma unroll
    for (int r = 0; r < 4; r++) {
      const float* ar = adj_base + (size_t)r * N_ + k0;
#pragma unroll
      for (int cb = 0; cb < 4; cb++) av[r][cb] = ar[cb * 16];
    }

#pragma unroll
    for (int i = 0; i < 8; i++) {
      const int fv = (i ^ fv_t) << 3;
      VT[scol + i][srow ^ fv] = v0[i];
      VT[scol + i][(srow + 32) ^ fv] = v1[i];
    }
    __syncthreads();

    // --- S = Q K^T (Q pre-scaled by 1/8) ---
    f32x4 s[4];
#pragma unroll
    for (int cb = 0; cb < 4; cb++) {
      f32x4 a = (f32x4){0.f, 0.f, 0.f, 0.f};
      const int row = cb * 16 + l15;
#pragma unroll
      for (int ks = 0; ks < 2; ks++) {
        bf16x8 kf = *(const bf16x8*)&Kt[row][((lg + 4 * ks) ^ (row & 7)) * 8];
        a = __builtin_amdgcn_mfma_f32_16x16x32_bf16(qf[ks], kf, a, 0, 0, 0);
      }
      s[cb] = a;
    }

    // --- mask + beta*adj, online softmax, P -> LDS ---
#pragma unroll
    for (int r = 0; r < 4; r++) {
      float tm = -__builtin_inff();
#pragma unroll
      for (int cb = 0; cb < 4; cb++) {
        const float a_ = av[r][cb];
        float sv = s[cb][r] + beta * a_;
        sv = (a_ > 0.f) ? sv : -9.0e15f;
        s[cb][r] = sv;
        tm = fmaxf(tm, sv);
      }
      tm = fmaxf(tm, __shfl_xor(tm, 1));
      tm = fmaxf(tm, __shfl_xor(tm, 2));
      tm = fmaxf(tm, __shfl_xor(tm, 4));
      tm = fmaxf(tm, __shfl_xor(tm, 8));

      const float mnew = fmaxf(mrow[r], tm);
      const float sc2 = __expf(mrow[r] - mnew);
      mrow[r] = mnew;
      float ps = 0.f;
#pragma unroll
      for (int cb = 0; cb < 4; cb++) {
        acc[cb][r] *= sc2;
        const float pf = __expf(s[cb][r] - mnew);
        const short pb = f2bf(pf);
        ps += bf2f(pb);
        Pt[w][4 * lg + r][cb * 16 + l15] = pb;
      }
      ps += __shfl_xor(ps, 1);
      ps += __shfl_xor(ps, 2);
      ps += __shfl_xor(ps, 4);
      ps += __shfl_xor(ps, 8);
      lrow[r] = lrow[r] * sc2 + ps;
    }

    // --- O += P @ V  (Pt is per-wave: no barrier needed) ---
#pragma unroll
    for (int ks = 0; ks < 2; ks++) {
      bf16x8 pa = *(const bf16x8*)&Pt[w][l15][8 * lg + 32 * ks];
#pragma unroll
      for (int cb = 0; cb < 4; cb++) {
        const int d = cb * 16 + l15;
        const int fv = ((d & 7) ^ ((d >> 3) & 7)) << 3;
        bf16x8 vb = *(const bf16x8*)&VT[d][(8 * lg + 32 * ks) ^ fv];
        acc[cb] = __builtin_amdgcn_mfma_f32_16x16x32_bf16(pa, vb, acc[cb], 0, 0, 0);
      }
    }
  }

  float inv[4];
#pragma unroll
  for (int r = 0; r < 4; r++) inv[r] = 1.f / lrow[r];
#pragma unroll
  for (int cb = 0; cb < 4; cb++) {
#pragma unroll
    for (int r = 0; r < 4; r++) {
      out[(seq0 + q0 + 16 * w + 4 * lg + r) * (size_t)D_ + hc + cb * 16 + l15] =
          acc[cb][r] * inv[r];
    }
  }
}

extern "C" void kernel_launch(void* const* d_in, const int* in_sizes, int n_in,
                              void* d_out, int out_size, void* d_ws, size_t ws_size,
                              hipStream_t stream) {
  const float* X    = (const float*)d_in[0];
  const float* adj  = (const float*)d_in[1];
  const float* Wq   = (const float*)d_in[2];
  const float* bq   = (const float*)d_in[3];
  const float* Wk   = (const float*)d_in[4];
  const float* bk   = (const float*)d_in[5];
  const float* Wv   = (const float*)d_in[6];
  const float* bv   = (const float*)d_in[7];
  const float* beta = (const float*)d_in[8];
  float* out = (float*)d_out;

  // workspace layout (bf16 shorts): Xb | Wt3 | QKV
  short* Xb  = (short*)d_ws;
  short* Wt3 = Xb + (size_t)(B_ * N_) * D_;
  short* QKV = Wt3 + 3 * (size_t)D_ * D_;

  cvt_x_kernel<<<dim3((B_ * N_ * D_) / (256 * 8)), 256, 0, stream>>>(X, Xb);
  cvt_w_kernel<<<dim3(24, 24, 3), dim3(32, 8), 0, stream>>>(Wq, Wk, Wv, Wt3);
  qkv_gemm_kernel<<<dim3(64, 6, 3), 256, 0, stream>>>(Xb, Wt3, bq, bk, bv, QKV);
  attn_kernel<<<dim3(16, 12, 8), 256, 0, stream>>>(QKV, adj, beta, out);
}

// Round 3
// 156.830 us; speedup vs baseline: 1.5355x; 1.5355x over previous
//
#include <hip/hip_runtime.h>

#define B_ 8
#define N_ 1024
#define D_ 768
#define H_ 12
#define HD_ 64

#define LOG2E 1.4426950408889634f

typedef __attribute__((ext_vector_type(8))) short bf16x8;
typedef __attribute__((ext_vector_type(4))) short short4_t;
typedef __attribute__((ext_vector_type(4))) float f32x4;
typedef unsigned int u32;

__device__ __forceinline__ short f2bf(float f) {
  union { float f; unsigned u; } v; v.f = f;
  unsigned u = v.u;
  unsigned r = u + 0x7fffu + ((u >> 16) & 1u);
  return (short)(r >> 16);
}
__device__ __forceinline__ float bf2f(short s) {
  union { unsigned u; float f; } v;
  v.u = ((unsigned)(unsigned short)s) << 16;
  return v.f;
}

// direct global -> LDS DMA, 16B per lane. LDS dest = wave-uniform base + lane*16.
__device__ __forceinline__ void gload_lds16(const void* g, void* l) {
  __builtin_amdgcn_global_load_lds((const __attribute__((address_space(1))) u32*)g,
                                   (__attribute__((address_space(3))) u32*)l, 16, 0, 0);
}

// ---------------- conversion: X f32 -> bf16 ----------------
__global__ void cvt_x_kernel(const float* __restrict__ X, short* __restrict__ Xb) {
  int i = (blockIdx.x * 256 + threadIdx.x) * 8;
  float4 a = *(const float4*)(X + i);
  float4 b = *(const float4*)(X + i + 4);
  bf16x8 o;
  o[0] = f2bf(a.x); o[1] = f2bf(a.y); o[2] = f2bf(a.z); o[3] = f2bf(a.w);
  o[4] = f2bf(b.x); o[5] = f2bf(b.y); o[6] = f2bf(b.z); o[7] = f2bf(b.w);
  *(bf16x8*)(Xb + i) = o;
}

// ---------------- conversion: W f32 -> bf16, transposed (Wt[n][k] = W[k][n]) ----------------
__global__ void cvt_w_kernel(const float* __restrict__ Wq, const float* __restrict__ Wk,
                             const float* __restrict__ Wv, short* __restrict__ Wt3) {
  const float* W = blockIdx.z == 0 ? Wq : (blockIdx.z == 1 ? Wk : Wv);
  short* O = Wt3 + (size_t)blockIdx.z * D_ * D_;
  __shared__ float t[32][33];
  int n0 = blockIdx.x * 32, k0 = blockIdx.y * 32;
  int tx = threadIdx.x, ty = threadIdx.y;
#pragma unroll
  for (int j = 0; j < 4; j++)
    t[ty + 8 * j][tx] = W[(size_t)(k0 + ty + 8 * j) * D_ + n0 + tx];
  __syncthreads();
#pragma unroll
  for (int j = 0; j < 4; j++)
    O[(size_t)(n0 + ty + 8 * j) * D_ + k0 + tx] = f2bf(t[tx][ty + 8 * j]);
}

// ---------------- madjF: fused mask/beta/log2e, MFMA C-fragment order, bf16 ----------------
// tile (b,qt,kt): thread t holds values for (q = qt*64 + 16w+4lg+r, k = kt*64 + cb*16+l15)
// stored at flat[tile*4096 + t*16 + cb*4 + r]
__global__ __launch_bounds__(256)
void madj_kernel(const float* __restrict__ adj, const float* __restrict__ beta_p,
                 short* __restrict__ madjF) {
  const int qt = blockIdx.x, kt = blockIdx.y, b = blockIdx.z;
  const int t = threadIdx.x;
  const int lane = t & 63, w = t >> 6;
  const int l15 = lane & 15, lg = lane >> 4;
  const float b2 = beta_p[0] * LOG2E;
  const float MASKV = -9.0e15f * LOG2E;

  const float* ap = adj + ((size_t)b * N_ + qt * 64 + 16 * w + 4 * lg) * (size_t)N_ + kt * 64 + l15;
  short vals[16];
#pragma unroll
  for (int r = 0; r < 4; r++) {
#pragma unroll
    for (int cb = 0; cb < 4; cb++) {
      float a = ap[(size_t)r * N_ + cb * 16];
      float m = (a > 0.f) ? b2 * a : MASKV;
      vals[cb * 4 + r] = f2bf(m);
    }
  }
  short* o = madjF + (((size_t)(b * 16 + qt) * 16 + kt) * 256 + t) * 16;
  bf16x8 lo, hi;
#pragma unroll
  for (int j = 0; j < 8; j++) { lo[j] = vals[j]; hi[j] = vals[8 + j]; }
  *(bf16x8*)o = lo;
  *(bf16x8*)(o + 8) = hi;
}

// ---------------- QKV projection GEMM: C = X @ W + b (bf16 out, Q pre-scaled) ----------------
__global__ __launch_bounds__(256, 4)
void qkv_gemm_kernel(const short* __restrict__ Xb, const short* __restrict__ Wt3,
                     const float* __restrict__ bq, const float* __restrict__ bk,
                     const float* __restrict__ bv, short* __restrict__ QKV) {
  const int z = blockIdx.z;
  const short* Wt = Wt3 + (size_t)z * D_ * D_;
  const float* bias = z == 0 ? bq : (z == 1 ? bk : bv);
  short* C = QKV + (size_t)z * (B_ * N_) * D_;
  const float alpha = (z == 0) ? 0.125f * LOG2E : 1.0f;

  const int m0 = blockIdx.x * 128;
  const int n0 = blockIdx.y * 128;
  const int tid = threadIdx.x;
  const int lane = tid & 63;
  const int wid = tid >> 6;
  const int wr = (wid >> 1) * 64;
  const int wc = (wid & 1) * 64;
  const int l15 = lane & 15;
  const int lg = lane >> 4;

  __shared__ short At[128][32];
  __shared__ short Bt[128][32];

  f32x4 acc[4][4];
#pragma unroll
  for (int m = 0; m < 4; m++)
#pragma unroll
    for (int n = 0; n < 4; n++)
      acc[m][n] = (f32x4){0.f, 0.f, 0.f, 0.f};

  const int srow_l = lane >> 2;
  const int sc8 = (((lane & 3) ^ ((lane >> 2) & 3)) * 8);

  for (int k0 = 0; k0 < D_; k0 += 32) {
    __syncthreads();
#pragma unroll
    for (int p = 0; p < 2; p++) {
      const int row = (wid + 4 * p) * 16 + srow_l;
      gload_lds16(Xb + (size_t)(m0 + row) * D_ + k0 + sc8,
                  ((short*)At) + (size_t)(wid + 4 * p) * 512);
      gload_lds16(Wt + (size_t)(n0 + row) * D_ + k0 + sc8,
                  ((short*)Bt) + (size_t)(wid + 4 * p) * 512);
    }
    __syncthreads();

    bf16x8 af[4], bfr[4];
#pragma unroll
    for (int m = 0; m < 4; m++) {
      const int row = wr + m * 16 + l15;
      af[m] = *(const bf16x8*)&At[row][(lg ^ (l15 & 3)) * 8];
    }
#pragma unroll
    for (int n = 0; n < 4; n++) {
      const int row = wc + n * 16 + l15;
      bfr[n] = *(const bf16x8*)&Bt[row][(lg ^ (l15 & 3)) * 8];
    }
#pragma unroll
    for (int m = 0; m < 4; m++)
#pragma unroll
      for (int n = 0; n < 4; n++)
        acc[m][n] = __builtin_amdgcn_mfma_f32_16x16x32_bf16(af[m], bfr[n], acc[m][n], 0, 0, 0);
  }

#pragma unroll
  for (int n = 0; n < 4; n++) {
    const int col = n0 + wc + n * 16 + l15;
    const float bval = bias[col];
#pragma unroll
    for (int m = 0; m < 4; m++) {
#pragma unroll
      for (int r = 0; r < 4; r++) {
        const int row = m0 + wr + m * 16 + 4 * lg + r;
        C[(size_t)row * D_ + col] = f2bf((acc[m][n][r] + bval) * alpha);
      }
    }
  }
}

// ---------------- V transpose: VTg[(b*12+h)*64 + d][n] = V[b][n][h*64+d] ----------------
__global__ __launch_bounds__(256)
void vT_kernel(const short* __restrict__ Vb, short* __restrict__ VTg) {
  const int nt = blockIdx.x, h = blockIdx.y, b = blockIdx.z;
  const int tid = threadIdx.x;
  __shared__ short st[64][68];
  const int n0 = nt * 64;
  {
    const int row = tid >> 2, c = (tid & 3) * 16;
    const short* p = Vb + ((size_t)b * N_ + n0 + row) * D_ + h * HD_ + c;
    *(bf16x8*)&st[row][c] = *(const bf16x8*)p;
    *(bf16x8*)&st[row][c + 8] = *(const bf16x8*)(p + 8);
  }
  __syncthreads();
  {
    const int d = tid >> 2, nb = (tid & 3) * 16;
    bf16x8 o0, o1;
#pragma unroll
    for (int i = 0; i < 8; i++) { o0[i] = st[nb + i][d]; o1[i] = st[nb + 8 + i][d]; }
    short* q = VTg + ((size_t)(b * H_ + h) * HD_ + d) * N_ + n0 + nb;
    *(bf16x8*)q = o0;
    *(bf16x8*)(q + 8) = o1;
  }
}

// ---------------- flash-style masked attention ----------------
__global__ __launch_bounds__(256, 4)
void attn_kernel(const short* __restrict__ QKV, const short* __restrict__ VTg,
                 const short* __restrict__ madjF, float* __restrict__ out) {
  const short* Qb = QKV;
  const short* Kb = QKV + (size_t)(B_ * N_) * D_;

  // XCD swizzle: 1536 blocks, chunk of 192 = one batch per XCD
  const int wg = blockIdx.x;
  const int swz = (wg & 7) * 192 + (wg >> 3);
  const int qt = swz & 15;
  const int h = (swz >> 4) % 12;
  const int b = swz / 192;

  const int tid = threadIdx.x;
  const int lane = tid & 63;
  const int w = tid >> 6;
  const int l15 = lane & 15;
  const int lg = lane >> 4;

  const int q0 = qt * 64;
  const size_t seq0 = (size_t)b * N_;
  const int hc = h * HD_;

  __shared__ short Kt[64][64];    // row k', phys chunk p holds logical chunk p^(k'&7)
  __shared__ short VTt[64][64];   // row d, swizzled same way over k-chunks
  __shared__ short Pt[4][16][68];

  bf16x8 qf[2];
  {
    const short* qp = Qb + (seq0 + q0 + 16 * w + l15) * (size_t)D_ + hc + 8 * lg;
    qf[0] = *(const bf16x8*)qp;
    qf[1] = *(const bf16x8*)(qp + 32);
  }
  bf16x8 ones;
#pragma unroll
  for (int i = 0; i < 8; i++) ones[i] = (short)0x3F80;

  f32x4 acc[4];
#pragma unroll
  for (int cb = 0; cb < 4; cb++) acc[cb] = (f32x4){0.f, 0.f, 0.f, 0.f};
  f32x4 lacc = (f32x4){0.f, 0.f, 0.f, 0.f};
  float mrow[4];
#pragma unroll
  for (int r = 0; r < 4; r++) mrow[r] = -__builtin_inff();

  // DMA source mapping (per wave): row 16w + (lane>>3) (+8 second pass), phys chunk lane&7
  const int krow = 16 * w + (lane >> 3);
  const int kc8 = ((lane & 7) ^ (lane >> 3)) * 8;
  const short* kg = Kb + (seq0 + krow) * (size_t)D_ + hc + kc8;
  const short* vg = VTg + ((size_t)(b * H_ + h) * HD_ + krow) * N_ + kc8;
  const short* mg = madjF + ((size_t)(b * 16 + qt) * 16) * 4096 + tid * 16;

  for (int kt = 0; kt < 16; kt++) {
    const int k0 = kt * 64;
    __syncthreads();

    // K tile: 2 DMA per wave
    gload_lds16(kg + (size_t)k0 * D_, ((short*)Kt) + (size_t)w * 1024);
    gload_lds16(kg + (size_t)(k0 + 8) * D_, ((short*)Kt) + (size_t)w * 1024 + 512);
    // V^T tile: 2 DMA per wave
    gload_lds16(vg + k0, ((short*)VTt) + (size_t)w * 1024);
    gload_lds16(vg + k0 + 8 * (size_t)N_, ((short*)VTt) + (size_t)w * 1024 + 512);
    // madj fragment (consumed as MFMA C-init)
    bf16x8 mlo = *(const bf16x8*)(mg + (size_t)kt * 4096);
    bf16x8 mhi = *(const bf16x8*)(mg + (size_t)kt * 4096 + 8);

    __syncthreads();

    // S = Q K^T + madj (all in log2 units; C-init carries beta*adj and mask)
    f32x4 s[4];
#pragma unroll
    for (int cb = 0; cb < 4; cb++) {
      f32x4 c;
#pragma unroll
      for (int r = 0; r < 4; r++)
        c[r] = bf2f(cb < 2 ? mlo[(cb & 1) * 4 + r] : mhi[(cb & 1) * 4 + r]);
      const int sw = l15 & 7;
      bf16x8 kf0 = *(const bf16x8*)&Kt[cb * 16 + l15][(lg ^ sw) * 8];
      bf16x8 kf1 = *(const bf16x8*)&Kt[cb * 16 + l15][((lg + 4) ^ sw) * 8];
      c = __builtin_amdgcn_mfma_f32_16x16x32_bf16(qf[0], kf0, c, 0, 0, 0);
      s[cb] = __builtin_amdgcn_mfma_f32_16x16x32_bf16(qf[1], kf1, c, 0, 0, 0);
    }

    // online softmax (exp2 domain), P -> LDS
#pragma unroll
    for (int r = 0; r < 4; r++) {
      float tm = fmaxf(fmaxf(s[0][r], s[1][r]), fmaxf(s[2][r], s[3][r]));
      tm = fmaxf(tm, __shfl_xor(tm, 1));
      tm = fmaxf(tm, __shfl_xor(tm, 2));
      tm = fmaxf(tm, __shfl_xor(tm, 4));
      tm = fmaxf(tm, __shfl_xor(tm, 8));
      const float mnew = fmaxf(mrow[r], tm);
      const float sc2 = __builtin_exp2f(mrow[r] - mnew);
      mrow[r] = mnew;
      lacc[r] *= sc2;
#pragma unroll
      for (int cb = 0; cb < 4; cb++) {
        acc[cb][r] *= sc2;
        const float pf = __builtin_exp2f(s[cb][r] - mnew);
        Pt[w][4 * lg + r][cb * 16 + l15] = f2bf(pf);
      }
    }

    // O += P @ V ; l += P @ 1   (Pt per-wave: no barrier)
#pragma unroll
    for (int ks = 0; ks < 2; ks++) {
      bf16x8 pa = *(const bf16x8*)&Pt[w][l15][8 * lg + 32 * ks];
      lacc = __builtin_amdgcn_mfma_f32_16x16x32_bf16(pa, ones, lacc, 0, 0, 0);
      const int sw = l15 & 7;
#pragma unroll
      for (int cb = 0; cb < 4; cb++) {
        bf16x8 vb = *(const bf16x8*)&VTt[cb * 16 + l15][((lg + 4 * ks) ^ sw) * 8];
        acc[cb] = __builtin_amdgcn_mfma_f32_16x16x32_bf16(pa, vb, acc[cb], 0, 0, 0);
      }
    }
  }

  float inv[4];
#pragma unroll
  for (int r = 0; r < 4; r++) inv[r] = 1.f / lacc[r];
#pragma unroll
  for (int cb = 0; cb < 4; cb++) {
#pragma unroll
    for (int r = 0; r < 4; r++) {
      out[(seq0 + q0 + 16 * w + 4 * lg + r) * (size_t)D_ + hc + cb * 16 + l15] =
          acc[cb][r] * inv[r];
    }
  }
}

extern "C" void kernel_launch(void* const* d_in, const int* in_sizes, int n_in,
                              void* d_out, int out_size, void* d_ws, size_t ws_size,
                              hipStream_t stream) {
  const float* X    = (const float*)d_in[0];
  const float* adj  = (const float*)d_in[1];
  const float* Wq   = (const float*)d_in[2];
  const float* bq   = (const float*)d_in[3];
  const float* Wk   = (const float*)d_in[4];
  const float* bk   = (const float*)d_in[5];
  const float* Wv   = (const float*)d_in[6];
  const float* bv   = (const float*)d_in[7];
  const float* beta = (const float*)d_in[8];
  float* out = (float*)d_out;

  // workspace (shorts): Xb | Wt3 | QKV | madjF ; VTg aliases Xb (dead after gemm)
  short* Xb    = (short*)d_ws;
  short* Wt3   = Xb + (size_t)(B_ * N_) * D_;
  short* QKV   = Wt3 + 3 * (size_t)D_ * D_;
  short* madjF = QKV + 3 * (size_t)(B_ * N_) * D_;
  short* VTg   = Xb;  // reuse: 8*12*64*1024 == 8*1024*768

  cvt_x_kernel<<<dim3((B_ * N_ * D_) / (256 * 8)), 256, 0, stream>>>(X, Xb);
  cvt_w_kernel<<<dim3(24, 24, 3), dim3(32, 8), 0, stream>>>(Wq, Wk, Wv, Wt3);
  madj_kernel<<<dim3(16, 16, 8), 256, 0, stream>>>(adj, beta, madjF);
  qkv_gemm_kernel<<<dim3(64, 6, 3), 256, 0, stream>>>(Xb, Wt3, bq, bk, bv, QKV);
  vT_kernel<<<dim3(16, 12, 8), 256, 0, stream>>>(QKV + 2 * (size_t)(B_ * N_) * D_, VTg);
  attn_kernel<<<dim3(1536), 256, 0, stream>>>(QKV, VTg, madjF, out);
}

// Round 4
// 135.050 us; speedup vs baseline: 1.7831x; 1.1613x over previous
//
#include <hip/hip_runtime.h>

#define B_ 8
#define N_ 1024
#define D_ 768
#define H_ 12
#define HD_ 64

#define LOG2E 1.4426950408889634f

typedef __attribute__((ext_vector_type(8))) short bf16x8;
typedef __attribute__((ext_vector_type(4))) short short4_t;
typedef __attribute__((ext_vector_type(4))) float f32x4;
typedef __attribute__((ext_vector_type(2))) unsigned int u32x2;
typedef unsigned int u32;

__device__ __forceinline__ short f2bf(float f) {
  union { float f; unsigned u; } v; v.f = f;
  unsigned u = v.u;
  unsigned r = u + 0x7fffu + ((u >> 16) & 1u);
  return (short)(r >> 16);
}
__device__ __forceinline__ float bf2f(short s) {
  union { unsigned u; float f; } v;
  v.u = ((unsigned)(unsigned short)s) << 16;
  return v.f;
}
__device__ __forceinline__ u32 fbits(float f) {
  union { float f; u32 u; } v; v.f = f; return v.u;
}
__device__ __forceinline__ float bpermf(int srclane, float x) {
  union { float f; int i; } v; v.f = x;
  union { int i; float f; } r;
  r.i = __builtin_amdgcn_ds_bpermute(srclane * 4, v.i);
  return r.f;
}

// direct global -> LDS DMA, 16B per lane. LDS dest = wave-uniform base + lane*16.
__device__ __forceinline__ void gload_lds16(const void* g, void* l) {
  __builtin_amdgcn_global_load_lds((const __attribute__((address_space(1))) u32*)g,
                                   (__attribute__((address_space(3))) u32*)l, 16, 0, 0);
}

// ---------------- conversion: X f32 -> bf16 ----------------
__global__ void cvt_x_kernel(const float* __restrict__ X, short* __restrict__ Xb) {
  int i = (blockIdx.x * 256 + threadIdx.x) * 8;
  float4 a = *(const float4*)(X + i);
  float4 b = *(const float4*)(X + i + 4);
  bf16x8 o;
  o[0] = f2bf(a.x); o[1] = f2bf(a.y); o[2] = f2bf(a.z); o[3] = f2bf(a.w);
  o[4] = f2bf(b.x); o[5] = f2bf(b.y); o[6] = f2bf(b.z); o[7] = f2bf(b.w);
  *(bf16x8*)(Xb + i) = o;
}

// ---------------- conversion: W f32 -> bf16, transposed (Wt[n][k] = W[k][n]) ----------------
__global__ void cvt_w_kernel(const float* __restrict__ Wq, const float* __restrict__ Wk,
                             const float* __restrict__ Wv, short* __restrict__ Wt3) {
  const float* W = blockIdx.z == 0 ? Wq : (blockIdx.z == 1 ? Wk : Wv);
  short* O = Wt3 + (size_t)blockIdx.z * D_ * D_;
  __shared__ float t[32][33];
  int n0 = blockIdx.x * 32, k0 = blockIdx.y * 32;
  int tx = threadIdx.x, ty = threadIdx.y;
#pragma unroll
  for (int j = 0; j < 4; j++)
    t[ty + 8 * j][tx] = W[(size_t)(k0 + ty + 8 * j) * D_ + n0 + tx];
  __syncthreads();
#pragma unroll
  for (int j = 0; j < 4; j++)
    O[(size_t)(n0 + ty + 8 * j) * D_ + k0 + tx] = f2bf(t[tx][ty + 8 * j]);
}

// ---------------- madjF: fused mask/beta/log2e, SWAPPED (S^T) fragment order, bf16 ----------
// attn thread t=(w,lg,l15) slot (cb,r) needs madj(q = qt*64+16w+l15, k = kt*64+16cb+4lg+r)
// stored at flat[((b*16+qt)*16+kt)*4096 + t*16 + cb*4 + r]
__global__ __launch_bounds__(256)
void madj_kernel(const float* __restrict__ adj, const float* __restrict__ beta_p,
                 short* __restrict__ madjF) {
  const int qt = blockIdx.x, kt = blockIdx.y, b = blockIdx.z;
  const int tid = threadIdx.x;
  const float b2 = beta_p[0] * LOG2E;
  const float MASKV = -9.0e15f * LOG2E;

  __shared__ float Lt[64][68];
  {
    const int row = tid >> 2, cs = (tid & 3) * 16;
    const float* ap = adj + ((size_t)b * N_ + qt * 64 + row) * (size_t)N_ + kt * 64 + cs;
#pragma unroll
    for (int j = 0; j < 4; j++)
      *(float4*)&Lt[row][cs + 4 * j] = *(const float4*)(ap + 4 * j);
  }
  __syncthreads();

  const int lane = tid & 63, w = tid >> 6;
  const int l15 = lane & 15, lg = lane >> 4;
  const int q = 16 * w + l15;
  short vals[16];
#pragma unroll
  for (int cb = 0; cb < 4; cb++) {
    float4 a4 = *(const float4*)&Lt[q][16 * cb + 4 * lg];
    float av[4] = {a4.x, a4.y, a4.z, a4.w};
#pragma unroll
    for (int r = 0; r < 4; r++) {
      float a = av[r];
      vals[cb * 4 + r] = f2bf((a > 0.f) ? b2 * a : MASKV);
    }
  }
  short* o = madjF + (((size_t)(b * 16 + qt) * 16 + kt) * 256 + tid) * 16;
  bf16x8 lo, hi;
#pragma unroll
  for (int j = 0; j < 8; j++) { lo[j] = vals[j]; hi[j] = vals[8 + j]; }
  *(bf16x8*)o = lo;
  *(bf16x8*)(o + 8) = hi;
}

// ---------------- QKV projection GEMM: C = X @ W + b (bf16 out, Q pre-scaled) ----------------
__global__ __launch_bounds__(256, 4)
void qkv_gemm_kernel(const short* __restrict__ Xb, const short* __restrict__ Wt3,
                     const float* __restrict__ bq, const float* __restrict__ bk,
                     const float* __restrict__ bv, short* __restrict__ QKV) {
  const int z = blockIdx.z;
  const short* Wt = Wt3 + (size_t)z * D_ * D_;
  const float* bias = z == 0 ? bq : (z == 1 ? bk : bv);
  short* C = QKV + (size_t)z * (B_ * N_) * D_;
  const float alpha = (z == 0) ? 0.125f * LOG2E : 1.0f;

  const int m0 = blockIdx.x * 128;
  const int n0 = blockIdx.y * 128;
  const int tid = threadIdx.x;
  const int lane = tid & 63;
  const int wid = tid >> 6;
  const int wr = (wid >> 1) * 64;
  const int wc = (wid & 1) * 64;
  const int l15 = lane & 15;
  const int lg = lane >> 4;

  __shared__ short At[128][32];
  __shared__ short Bt[128][32];

  f32x4 acc[4][4];
#pragma unroll
  for (int m = 0; m < 4; m++)
#pragma unroll
    for (int n = 0; n < 4; n++)
      acc[m][n] = (f32x4){0.f, 0.f, 0.f, 0.f};

  const int srow_l = lane >> 2;
  const int sc8 = (((lane & 3) ^ ((lane >> 2) & 3)) * 8);

  for (int k0 = 0; k0 < D_; k0 += 32) {
    __syncthreads();
#pragma unroll
    for (int p = 0; p < 2; p++) {
      const int row = (wid + 4 * p) * 16 + srow_l;
      gload_lds16(Xb + (size_t)(m0 + row) * D_ + k0 + sc8,
                  ((short*)At) + (size_t)(wid + 4 * p) * 512);
      gload_lds16(Wt + (size_t)(n0 + row) * D_ + k0 + sc8,
                  ((short*)Bt) + (size_t)(wid + 4 * p) * 512);
    }
    __syncthreads();

    bf16x8 af[4], bfr[4];
#pragma unroll
    for (int m = 0; m < 4; m++) {
      const int row = wr + m * 16 + l15;
      af[m] = *(const bf16x8*)&At[row][(lg ^ (l15 & 3)) * 8];
    }
#pragma unroll
    for (int n = 0; n < 4; n++) {
      const int row = wc + n * 16 + l15;
      bfr[n] = *(const bf16x8*)&Bt[row][(lg ^ (l15 & 3)) * 8];
    }
#pragma unroll
    for (int m = 0; m < 4; m++)
#pragma unroll
      for (int n = 0; n < 4; n++)
        acc[m][n] = __builtin_amdgcn_mfma_f32_16x16x32_bf16(af[m], bfr[n], acc[m][n], 0, 0, 0);
  }

#pragma unroll
  for (int n = 0; n < 4; n++) {
    const int col = n0 + wc + n * 16 + l15;
    const float bval = bias[col];
#pragma unroll
    for (int m = 0; m < 4; m++) {
#pragma unroll
      for (int r = 0; r < 4; r++) {
        const int row = m0 + wr + m * 16 + 4 * lg + r;
        C[(size_t)row * D_ + col] = f2bf((acc[m][n][r] + bval) * alpha);
      }
    }
  }
}

// ---------------- V transpose: VTg[(b*12+h)*64 + d][n] = V[b][n][h*64+d] ----------------
__global__ __launch_bounds__(256)
void vT_kernel(const short* __restrict__ Vb, short* __restrict__ VTg) {
  const int nt = blockIdx.x, h = blockIdx.y, b = blockIdx.z;
  const int tid = threadIdx.x;
  __shared__ short st[64][68];
  const int n0 = nt * 64;
  {
    const int row = tid >> 2, c = (tid & 3) * 16;
    const short* p = Vb + ((size_t)b * N_ + n0 + row) * D_ + h * HD_ + c;
    *(bf16x8*)&st[row][c] = *(const bf16x8*)p;
    *(bf16x8*)&st[row][c + 8] = *(const bf16x8*)(p + 8);
  }
  __syncthreads();
  {
    const int d = tid >> 2, nb = (tid & 3) * 16;
    bf16x8 o0, o1;
#pragma unroll
    for (int i = 0; i < 8; i++) { o0[i] = st[nb + i][d]; o1[i] = st[nb + 8 + i][d]; }
    short* q = VTg + ((size_t)(b * H_ + h) * HD_ + d) * N_ + n0 + nb;
    *(bf16x8*)q = o0;
    *(bf16x8*)(q + 8) = o1;
  }
}

// ---------------- flash-style masked attention (swapped-QK, lane-local softmax) ------------
__global__ __launch_bounds__(256, 4)
void attn_kernel(const short* __restrict__ QKV, const short* __restrict__ VTg,
                 const short* __restrict__ madjF, float* __restrict__ out) {
  const short* Qb = QKV;
  const short* Kb = QKV + (size_t)(B_ * N_) * D_;

  // XCD swizzle: 1536 blocks, chunk of 192 = one batch per XCD
  const int wg = blockIdx.x;
  const int swz = (wg & 7) * 192 + (wg >> 3);
  const int qt = swz & 15;
  const int h = (swz >> 4) % 12;
  const int b = swz / 192;

  const int tid = threadIdx.x;
  const int lane = tid & 63;
  const int w = tid >> 6;
  const int l15 = lane & 15;
  const int lg = lane >> 4;

  const int q0 = qt * 64;
  const size_t seq0 = (size_t)b * N_;
  const int hc = h * HD_;

  __shared__ short Kt[64][64];    // row k', phys 16B-chunk p holds logical chunk p^(k'&7)
  __shared__ short VTt[64][64];   // row d, same swizzle over k-chunks
  __shared__ short Pt[4][16][64]; // per-wave; row q, 8B-chunk c at phys c^((q&7)<<1)

  bf16x8 qf[2];
  {
    const short* qp = Qb + (seq0 + q0 + 16 * w + l15) * (size_t)D_ + hc + 8 * lg;
    qf[0] = *(const bf16x8*)qp;
    qf[1] = *(const bf16x8*)(qp + 32);
  }

  f32x4 acc[4];
#pragma unroll
  for (int cb = 0; cb < 4; cb++) acc[cb] = (f32x4){0.f, 0.f, 0.f, 0.f};
  float m_ = -__builtin_inff();
  float l_ = 0.f;

  const int krow = 16 * w + (lane >> 3);
  const int kc8 = ((lane & 7) ^ (lane >> 3)) * 8;
  const short* kg = Kb + (seq0 + krow) * (size_t)D_ + hc + kc8;
  const short* vg = VTg + ((size_t)(b * H_ + h) * HD_ + krow) * N_ + kc8;
  const short* mg = madjF + ((size_t)(b * 16 + qt) * 16) * 4096 + tid * 16;

  const int sw2 = (l15 & 7) << 1;           // Pt chunk swizzle for row q=l15
  char* ptrow = (char*)&Pt[w][l15][0];      // write row (q = l15)

  for (int kt = 0; kt < 16; kt++) {
    const int k0 = kt * 64;
    __syncthreads();

    gload_lds16(kg + (size_t)k0 * D_, ((short*)Kt) + (size_t)w * 1024);
    gload_lds16(kg + (size_t)(k0 + 8) * D_, ((short*)Kt) + (size_t)w * 1024 + 512);
    gload_lds16(vg + k0, ((short*)VTt) + (size_t)w * 1024);
    gload_lds16(vg + k0 + 8 * (size_t)N_, ((short*)VTt) + (size_t)w * 1024 + 512);
    bf16x8 mlo = *(const bf16x8*)(mg + (size_t)kt * 4096);
    bf16x8 mhi = *(const bf16x8*)(mg + (size_t)kt * 4096 + 8);

    __syncthreads();

    // S^T = K Q^T + madj  (lane holds S[q=l15][k=16cb+4lg+r], log2 units)
    f32x4 s[4];
#pragma unroll
    for (int cb = 0; cb < 4; cb++) {
      f32x4 c;
#pragma unroll
      for (int r = 0; r < 4; r++)
        c[r] = bf2f(cb < 2 ? mlo[(cb & 1) * 4 + r] : mhi[(cb & 1) * 4 + r]);
      const int swk = l15 & 7;
      bf16x8 kf0 = *(const bf16x8*)&Kt[cb * 16 + l15][(lg ^ swk) * 8];
      bf16x8 kf1 = *(const bf16x8*)&Kt[cb * 16 + l15][((lg + 4) ^ swk) * 8];
      c = __builtin_amdgcn_mfma_f32_16x16x32_bf16(kf0, qf[0], c, 0, 0, 0);
      s[cb] = __builtin_amdgcn_mfma_f32_16x16x32_bf16(kf1, qf[1], c, 0, 0, 0);
    }

    // lane-local row max (16 values) + reduce over lg (lanes ^16, ^32)
    float tm = fmaxf(fmaxf(fmaxf(s[0][0], s[0][1]), fmaxf(s[0][2], s[0][3])),
                     fmaxf(fmaxf(s[1][0], s[1][1]), fmaxf(s[1][2], s[1][3])));
    float tm2 = fmaxf(fmaxf(fmaxf(s[2][0], s[2][1]), fmaxf(s[2][2], s[2][3])),
                      fmaxf(fmaxf(s[3][0], s[3][1]), fmaxf(s[3][2], s[3][3])));
    tm = fmaxf(tm, tm2);
    tm = fmaxf(tm, __shfl_xor(tm, 16));
    tm = fmaxf(tm, __shfl_xor(tm, 32));

    // defer-max: rescale only when the max actually grew past THR=8 (log2 units)
    if (!__all(tm <= m_ + 8.f)) {
      const float mnew = fmaxf(m_, tm);
      const float sc2 = __builtin_exp2f(m_ - mnew);
      m_ = mnew;
      l_ *= sc2;
      float scr[4];
#pragma unroll
      for (int r = 0; r < 4; r++) scr[r] = bpermf(4 * lg + r, sc2);
#pragma unroll
      for (int cb = 0; cb < 4; cb++)
#pragma unroll
        for (int r = 0; r < 4; r++) acc[cb][r] *= scr[r];
    }

    // P = exp2(s - m), packed to bf16 pairs (round-half-up), row-sum in-register
    float ps = 0.f;
    u32 pk[8];
#pragma unroll
    for (int cb = 0; cb < 4; cb++) {
#pragma unroll
      for (int rp = 0; rp < 2; rp++) {
        const float p0 = __builtin_exp2f(s[cb][2 * rp] - m_);
        const float p1 = __builtin_exp2f(s[cb][2 * rp + 1] - m_);
        ps += p0 + p1;
        pk[cb * 2 + rp] =
            __builtin_amdgcn_perm(fbits(p1) + 0x8000u, fbits(p0) + 0x8000u, 0x07060302u);
      }
    }
    ps += __shfl_xor(ps, 16);
    ps += __shfl_xor(ps, 32);
    l_ += ps;

    // Pt write: chunk (4cb+lg) ^ sw2, 8B per cb
#pragma unroll
    for (int cb = 0; cb < 4; cb++) {
      u32x2 wv = {pk[2 * cb], pk[2 * cb + 1]};
      *(u32x2*)(ptrow + (((4 * cb + lg) ^ sw2) << 3)) = wv;
    }

    // O += P @ V   (Pt per-wave: no barrier)
#pragma unroll
    for (int ks = 0; ks < 2; ks++) {
      bf16x8 pa = *(const bf16x8*)(ptrow + ((((lg << 1) + 8 * ks) ^ sw2) << 3));
#pragma unroll
      for (int cb = 0; cb < 4; cb++) {
        const int row = cb * 16 + l15;
        bf16x8 vb = *(const bf16x8*)&VTt[row][((lg + 4 * ks) ^ (row & 7)) * 8];
        acc[cb] = __builtin_amdgcn_mfma_f32_16x16x32_bf16(pa, vb, acc[cb], 0, 0, 0);
      }
    }
  }

  // bring 1/l from softmax layout (q=l15) to accumulator layout (q=4lg+r)
  float inv[4];
#pragma unroll
  for (int r = 0; r < 4; r++) inv[r] = 1.f / bpermf(4 * lg + r, l_);
#pragma unroll
  for (int cb = 0; cb < 4; cb++) {
#pragma unroll
    for (int r = 0; r < 4; r++) {
      out[(seq0 + q0 + 16 * w + 4 * lg + r) * (size_t)D_ + hc + cb * 16 + l15] =
          acc[cb][r] * inv[r];
    }
  }
}

extern "C" void kernel_launch(void* const* d_in, const int* in_sizes, int n_in,
                              void* d_out, int out_size, void* d_ws, size_t ws_size,
                              hipStream_t stream) {
  const float* X    = (const float*)d_in[0];
  const float* adj  = (const float*)d_in[1];
  const float* Wq   = (const float*)d_in[2];
  const float* bq   = (const float*)d_in[3];
  const float* Wk   = (const float*)d_in[4];
  const float* bk   = (const float*)d_in[5];
  const float* Wv   = (const float*)d_in[6];
  const float* bv   = (const float*)d_in[7];
  const float* beta = (const float*)d_in[8];
  float* out = (float*)d_out;

  // workspace (shorts): Xb | Wt3 | QKV | madjF ; VTg aliases Xb (dead after gemm)
  short* Xb    = (short*)d_ws;
  short* Wt3   = Xb + (size_t)(B_ * N_) * D_;
  short* QKV   = Wt3 + 3 * (size_t)D_ * D_;
  short* madjF = QKV + 3 * (size_t)(B_ * N_) * D_;
  short* VTg   = Xb;  // reuse: 8*12*64*1024 == 8*1024*768

  cvt_x_kernel<<<dim3((B_ * N_ * D_) / (256 * 8)), 256, 0, stream>>>(X, Xb);
  cvt_w_kernel<<<dim3(24, 24, 3), dim3(32, 8), 0, stream>>>(Wq, Wk, Wv, Wt3);
  madj_kernel<<<dim3(16, 16, 8), 256, 0, stream>>>(adj, beta, madjF);
  qkv_gemm_kernel<<<dim3(64, 6, 3), 256, 0, stream>>>(Xb, Wt3, bq, bk, bv, QKV);
  vT_kernel<<<dim3(16, 12, 8), 256, 0, stream>>>(QKV + 2 * (size_t)(B_ * N_) * D_, VTg);
  attn_kernel<<<dim3(1536), 256, 0, stream>>>(QKV, VTg, madjF, out);
}

// Round 5
// 131.221 us; speedup vs baseline: 1.8351x; 1.0292x over previous
//
#include <hip/hip_runtime.h>

#define B_ 8
#define N_ 1024
#define D_ 768
#define H_ 12
#define HD_ 64

#define LOG2E 1.4426950408889634f

typedef __attribute__((ext_vector_type(8))) short bf16x8;
typedef __attribute__((ext_vector_type(4))) short short4_t;
typedef __attribute__((ext_vector_type(4))) float f32x4;
typedef __attribute__((ext_vector_type(2))) unsigned int u32x2;
typedef unsigned int u32;

__device__ __forceinline__ short f2bf(float f) {
  union { float f; unsigned u; } v; v.f = f;
  unsigned u = v.u;
  unsigned r = u + 0x7fffu + ((u >> 16) & 1u);
  return (short)(r >> 16);
}
__device__ __forceinline__ float bf2f(short s) {
  union { unsigned u; float f; } v;
  v.u = ((unsigned)(unsigned short)s) << 16;
  return v.f;
}
__device__ __forceinline__ float bpermf(int srclane, float x) {
  union { float f; int i; } v; v.f = x;
  union { int i; float f; } r;
  r.i = __builtin_amdgcn_ds_bpermute(srclane * 4, v.i);
  return r.f;
}
__device__ __forceinline__ float max3f(float a, float b, float c) {
  return fmaxf(fmaxf(a, b), c);   // clang fuses to v_max3_f32
}
// packed bf16 pair: low = cvt(a), high = cvt(b); RNE rounding
__device__ __forceinline__ u32 cvtpk(float a, float b) {
  u32 r;
  asm("v_cvt_pk_bf16_f32 %0, %1, %2" : "=v"(r) : "v"(a), "v"(b));
  return r;
}

// direct global -> LDS DMA, 16B per lane. LDS dest = wave-uniform base + lane*16.
__device__ __forceinline__ void gload_lds16(const void* g, void* l) {
  __builtin_amdgcn_global_load_lds((const __attribute__((address_space(1))) u32*)g,
                                   (__attribute__((address_space(3))) u32*)l, 16, 0, 0);
}

// ---------------- conversion: X f32 -> bf16 ----------------
__global__ void cvt_x_kernel(const float* __restrict__ X, short* __restrict__ Xb) {
  int i = (blockIdx.x * 256 + threadIdx.x) * 8;
  float4 a = *(const float4*)(X + i);
  float4 b = *(const float4*)(X + i + 4);
  bf16x8 o;
  o[0] = f2bf(a.x); o[1] = f2bf(a.y); o[2] = f2bf(a.z); o[3] = f2bf(a.w);
  o[4] = f2bf(b.x); o[5] = f2bf(b.y); o[6] = f2bf(b.z); o[7] = f2bf(b.w);
  *(bf16x8*)(Xb + i) = o;
}

// ---------------- conversion: W f32 -> bf16, transposed (Wt[n][k] = W[k][n]) ----------------
__global__ void cvt_w_kernel(const float* __restrict__ Wq, const float* __restrict__ Wk,
                             const float* __restrict__ Wv, short* __restrict__ Wt3) {
  const float* W = blockIdx.z == 0 ? Wq : (blockIdx.z == 1 ? Wk : Wv);
  short* O = Wt3 + (size_t)blockIdx.z * D_ * D_;
  __shared__ float t[32][33];
  int n0 = blockIdx.x * 32, k0 = blockIdx.y * 32;
  int tx = threadIdx.x, ty = threadIdx.y;
#pragma unroll
  for (int j = 0; j < 4; j++)
    t[ty + 8 * j][tx] = W[(size_t)(k0 + ty + 8 * j) * D_ + n0 + tx];
  __syncthreads();
#pragma unroll
  for (int j = 0; j < 4; j++)
    O[(size_t)(n0 + ty + 8 * j) * D_ + k0 + tx] = f2bf(t[tx][ty + 8 * j]);
}

// ---------------- madjF: fused mask/beta/log2e, SWAPPED (S^T) fragment order, bf16 ----------
// attn thread t=(w,lg,l15) slot (cb,r) needs madj(q = qt*64+16w+l15, k = kt*64+16cb+4lg+r)
// stored at flat[((b*16+qt)*16+kt)*4096 + t*16 + cb*4 + r]
__global__ __launch_bounds__(256)
void madj_kernel(const float* __restrict__ adj, const float* __restrict__ beta_p,
                 short* __restrict__ madjF) {
  const int qt = blockIdx.x, kt = blockIdx.y, b = blockIdx.z;
  const int tid = threadIdx.x;
  const float b2 = beta_p[0] * LOG2E;
  const float MASKV = -9.0e15f * LOG2E;

  __shared__ float Lt[64][68];
  {
    const int row = tid >> 2, cs = (tid & 3) * 16;
    const float* ap = adj + ((size_t)b * N_ + qt * 64 + row) * (size_t)N_ + kt * 64 + cs;
#pragma unroll
    for (int j = 0; j < 4; j++)
      *(float4*)&Lt[row][cs + 4 * j] = *(const float4*)(ap + 4 * j);
  }
  __syncthreads();

  const int lane = tid & 63, w = tid >> 6;
  const int l15 = lane & 15, lg = lane >> 4;
  const int q = 16 * w + l15;
  short vals[16];
#pragma unroll
  for (int cb = 0; cb < 4; cb++) {
    float4 a4 = *(const float4*)&Lt[q][16 * cb + 4 * lg];
    float av[4] = {a4.x, a4.y, a4.z, a4.w};
#pragma unroll
    for (int r = 0; r < 4; r++) {
      float a = av[r];
      vals[cb * 4 + r] = f2bf((a > 0.f) ? b2 * a : MASKV);
    }
  }
  short* o = madjF + (((size_t)(b * 16 + qt) * 16 + kt) * 256 + tid) * 16;
  bf16x8 lo, hi;
#pragma unroll
  for (int j = 0; j < 8; j++) { lo[j] = vals[j]; hi[j] = vals[8 + j]; }
  *(bf16x8*)o = lo;
  *(bf16x8*)(o + 8) = hi;
}

// ---------------- QKV projection GEMM: C = X @ W + b (bf16 out, Q pre-scaled) ----------------
// double-buffered LDS, one barrier per K-step
__global__ __launch_bounds__(256, 4)
void qkv_gemm_kernel(const short* __restrict__ Xb, const short* __restrict__ Wt3,
                     const float* __restrict__ bq, const float* __restrict__ bk,
                     const float* __restrict__ bv, short* __restrict__ QKV) {
  const int z = blockIdx.z;
  const short* Wt = Wt3 + (size_t)z * D_ * D_;
  const float* bias = z == 0 ? bq : (z == 1 ? bk : bv);
  short* C = QKV + (size_t)z * (B_ * N_) * D_;
  const float alpha = (z == 0) ? 0.125f * LOG2E : 1.0f;

  const int m0 = blockIdx.x * 128;
  const int n0 = blockIdx.y * 128;
  const int tid = threadIdx.x;
  const int lane = tid & 63;
  const int wid = tid >> 6;
  const int wr = (wid >> 1) * 64;
  const int wc = (wid & 1) * 64;
  const int l15 = lane & 15;
  const int lg = lane >> 4;

  __shared__ short At[2][128][32];
  __shared__ short Bt[2][128][32];

  f32x4 acc[4][4];
#pragma unroll
  for (int m = 0; m < 4; m++)
#pragma unroll
    for (int n = 0; n < 4; n++)
      acc[m][n] = (f32x4){0.f, 0.f, 0.f, 0.f};

  const int srow_l = lane >> 2;
  const int sc8 = (((lane & 3) ^ ((lane >> 2) & 3)) * 8);
  const short* ag = Xb + (size_t)(m0 + wid * 16 + srow_l) * D_ + sc8;
  const short* bg = Wt + (size_t)(n0 + wid * 16 + srow_l) * D_ + sc8;

  auto stage = [&](int bi, int k0) {
#pragma unroll
    for (int p = 0; p < 2; p++) {
      gload_lds16(ag + (size_t)(64 * p) * D_ + k0,
                  ((short*)At[bi]) + (size_t)(wid + 4 * p) * 512);
      gload_lds16(bg + (size_t)(64 * p) * D_ + k0,
                  ((short*)Bt[bi]) + (size_t)(wid + 4 * p) * 512);
    }
  };

  stage(0, 0);
  for (int k0 = 0; k0 < D_; k0 += 32) {
    const int cur = (k0 >> 5) & 1;
    __syncthreads();                       // drains vmcnt: buf[cur] ready
    if (k0 + 32 < D_) stage(cur ^ 1, k0 + 32);

    bf16x8 af[4], bfr[4];
#pragma unroll
    for (int m = 0; m < 4; m++) {
      const int row = wr + m * 16 + l15;
      af[m] = *(const bf16x8*)&At[cur][row][(lg ^ (l15 & 3)) * 8];
    }
#pragma unroll
    for (int n = 0; n < 4; n++) {
      const int row = wc + n * 16 + l15;
      bfr[n] = *(const bf16x8*)&Bt[cur][row][(lg ^ (l15 & 3)) * 8];
    }
#pragma unroll
    for (int m = 0; m < 4; m++)
#pragma unroll
      for (int n = 0; n < 4; n++)
        acc[m][n] = __builtin_amdgcn_mfma_f32_16x16x32_bf16(af[m], bfr[n], acc[m][n], 0, 0, 0);
  }

#pragma unroll
  for (int n = 0; n < 4; n++) {
    const int col = n0 + wc + n * 16 + l15;
    const float bval = bias[col];
#pragma unroll
    for (int m = 0; m < 4; m++) {
#pragma unroll
      for (int r = 0; r < 4; r++) {
        const int row = m0 + wr + m * 16 + 4 * lg + r;
        C[(size_t)row * D_ + col] = f2bf((acc[m][n][r] + bval) * alpha);
      }
    }
  }
}

// ---------------- V transpose: VTg[(b*12+h)*64 + d][n] = V[b][n][h*64+d] ----------------
__global__ __launch_bounds__(256)
void vT_kernel(const short* __restrict__ Vb, short* __restrict__ VTg) {
  const int nt = blockIdx.x, h = blockIdx.y, b = blockIdx.z;
  const int tid = threadIdx.x;
  __shared__ short st[64][68];
  const int n0 = nt * 64;
  {
    const int row = tid >> 2, c = (tid & 3) * 16;
    const short* p = Vb + ((size_t)b * N_ + n0 + row) * D_ + h * HD_ + c;
    *(bf16x8*)&st[row][c] = *(const bf16x8*)p;
    *(bf16x8*)&st[row][c + 8] = *(const bf16x8*)(p + 8);
  }
  __syncthreads();
  {
    const int d = tid >> 2, nb = (tid & 3) * 16;
    bf16x8 o0, o1;
#pragma unroll
    for (int i = 0; i < 8; i++) { o0[i] = st[nb + i][d]; o1[i] = st[nb + 8 + i][d]; }
    short* q = VTg + ((size_t)(b * H_ + h) * HD_ + d) * N_ + n0 + nb;
    *(bf16x8*)q = o0;
    *(bf16x8*)(q + 8) = o1;
  }
}

// ---------------- flash-style masked attention (swapped-QK, dbuf, lane-local softmax) ------
__global__ __launch_bounds__(256, 4)
void attn_kernel(const short* __restrict__ QKV, const short* __restrict__ VTg,
                 const short* __restrict__ madjF, float* __restrict__ out) {
  const short* Qb = QKV;
  const short* Kb = QKV + (size_t)(B_ * N_) * D_;

  // XCD swizzle: 1536 blocks, chunk of 192 = one batch per XCD
  const int wg = blockIdx.x;
  const int swz = (wg & 7) * 192 + (wg >> 3);
  const int qt = swz & 15;
  const int h = (swz >> 4) % 12;
  const int b = swz / 192;

  const int tid = threadIdx.x;
  const int lane = tid & 63;
  const int w = tid >> 6;
  const int l15 = lane & 15;
  const int lg = lane >> 4;

  const int q0 = qt * 64;
  const size_t seq0 = (size_t)b * N_;
  const int hc = h * HD_;

  __shared__ short Kt[2][64][64];    // row k', phys 16B-chunk p holds logical chunk p^(k'&7)
  __shared__ short VTt[2][64][64];   // row d, same swizzle over k-chunks
  __shared__ short Pt[4][16][64];    // per-wave; row q, 8B-chunk c at phys c^((q&7)<<1)

  bf16x8 qf[2];
  {
    const short* qp = Qb + (seq0 + q0 + 16 * w + l15) * (size_t)D_ + hc + 8 * lg;
    qf[0] = *(const bf16x8*)qp;
    qf[1] = *(const bf16x8*)(qp + 32);
  }

  f32x4 acc[4];
#pragma unroll
  for (int cb = 0; cb < 4; cb++) acc[cb] = (f32x4){0.f, 0.f, 0.f, 0.f};
  float m_ = -__builtin_inff();
  float l_ = 0.f;

  const int krow = 16 * w + (lane >> 3);
  const int kc8 = ((lane & 7) ^ (lane >> 3)) * 8;
  const short* kg = Kb + (seq0 + krow) * (size_t)D_ + hc + kc8;
  const short* vg = VTg + ((size_t)(b * H_ + h) * HD_ + krow) * N_ + kc8;
  const short* mg = madjF + ((size_t)(b * 16 + qt) * 16) * 4096 + tid * 16;

  const int sw2 = (l15 & 7) << 1;           // Pt chunk swizzle for row q=l15
  char* ptrow = (char*)&Pt[w][l15][0];      // write row (q = l15)

  auto stage = [&](int bi, int kt) {
    const int k0 = kt * 64;
    gload_lds16(kg + (size_t)k0 * D_, ((short*)Kt[bi]) + (size_t)w * 1024);
    gload_lds16(kg + (size_t)(k0 + 8) * D_, ((short*)Kt[bi]) + (size_t)w * 1024 + 512);
    gload_lds16(vg + k0, ((short*)VTt[bi]) + (size_t)w * 1024);
    gload_lds16(vg + k0 + 8 * (size_t)N_, ((short*)VTt[bi]) + (size_t)w * 1024 + 512);
  };

  stage(0, 0);
  bf16x8 mlo = *(const bf16x8*)mg;
  bf16x8 mhi = *(const bf16x8*)(mg + 8);

  for (int kt = 0; kt < 16; kt++) {
    const int cur = kt & 1;
    __syncthreads();                        // drains vmcnt: buf[cur] staged, prev reads done
    if (kt < 15) stage(cur ^ 1, kt + 1);
    const int ktn = kt < 15 ? kt + 1 : 15;
    bf16x8 mlo2 = *(const bf16x8*)(mg + (size_t)ktn * 4096);
    bf16x8 mhi2 = *(const bf16x8*)(mg + (size_t)ktn * 4096 + 8);

    // S^T = K Q^T + madj  (lane holds S[q=l15][k=16cb+4lg+r], log2 units)
    f32x4 s[4];
#pragma unroll
    for (int cb = 0; cb < 4; cb++) {
      f32x4 c;
#pragma unroll
      for (int r = 0; r < 4; r++)
        c[r] = bf2f(cb < 2 ? mlo[(cb & 1) * 4 + r] : mhi[(cb & 1) * 4 + r]);
      const int swk = l15 & 7;
      bf16x8 kf0 = *(const bf16x8*)&Kt[cur][cb * 16 + l15][(lg ^ swk) * 8];
      bf16x8 kf1 = *(const bf16x8*)&Kt[cur][cb * 16 + l15][((lg + 4) ^ swk) * 8];
      c = __builtin_amdgcn_mfma_f32_16x16x32_bf16(kf0, qf[0], c, 0, 0, 0);
      s[cb] = __builtin_amdgcn_mfma_f32_16x16x32_bf16(kf1, qf[1], c, 0, 0, 0);
    }
    mlo = mlo2; mhi = mhi2;

    // lane-local row max (16 values, max3 tree) + reduce over lg (lanes ^16, ^32)
    float tm = max3f(max3f(s[0][0], s[0][1], s[0][2]),
                     max3f(s[0][3], s[1][0], s[1][1]),
                     max3f(s[1][2], s[1][3], s[2][0]));
    float tm2 = max3f(max3f(s[2][1], s[2][2], s[2][3]),
                      max3f(s[3][0], s[3][1], s[3][2]), s[3][3]);
    tm = fmaxf(tm, tm2);
    tm = fmaxf(tm, __shfl_xor(tm, 16));
    tm = fmaxf(tm, __shfl_xor(tm, 32));

    // defer-max: rescale only when the max actually grew past THR=8 (log2 units)
    if (!__all(tm <= m_ + 8.f)) {
      const float mnew = fmaxf(m_, tm);
      const float sc2 = __builtin_exp2f(m_ - mnew);
      m_ = mnew;
      l_ *= sc2;
      float scr[4];
#pragma unroll
      for (int r = 0; r < 4; r++) scr[r] = bpermf(4 * lg + r, sc2);
#pragma unroll
      for (int cb = 0; cb < 4; cb++)
#pragma unroll
        for (int r = 0; r < 4; r++) acc[cb][r] *= scr[r];
    }

    // P = exp2(s - m), packed bf16 pairs via v_cvt_pk_bf16_f32, row-sum in-register
    float ps = 0.f;
    u32 pk[8];
#pragma unroll
    for (int cb = 0; cb < 4; cb++) {
#pragma unroll
      for (int rp = 0; rp < 2; rp++) {
        const float p0 = __builtin_exp2f(s[cb][2 * rp] - m_);
        const float p1 = __builtin_exp2f(s[cb][2 * rp + 1] - m_);
        ps += p0 + p1;
        pk[cb * 2 + rp] = cvtpk(p0, p1);
      }
    }
    ps += __shfl_xor(ps, 16);
    ps += __shfl_xor(ps, 32);
    l_ += ps;

    // Pt write: chunk (4cb+lg) ^ sw2, 8B per cb
#pragma unroll
    for (int cb = 0; cb < 4; cb++) {
      u32x2 wv = {pk[2 * cb], pk[2 * cb + 1]};
      *(u32x2*)(ptrow + (((4 * cb + lg) ^ sw2) << 3)) = wv;
    }

    // O += P @ V   (Pt per-wave: no barrier)
#pragma unroll
    for (int ks = 0; ks < 2; ks++) {
      bf16x8 pa = *(const bf16x8*)(ptrow + ((((lg << 1) + 8 * ks) ^ sw2) << 3));
#pragma unroll
      for (int cb = 0; cb < 4; cb++) {
        const int row = cb * 16 + l15;
        bf16x8 vb = *(const bf16x8*)&VTt[cur][row][((lg + 4 * ks) ^ (row & 7)) * 8];
        acc[cb] = __builtin_amdgcn_mfma_f32_16x16x32_bf16(pa, vb, acc[cb], 0, 0, 0);
      }
    }
  }

  // bring 1/l from softmax layout (q=l15) to accumulator layout (q=4lg+r)
  float inv[4];
#pragma unroll
  for (int r = 0; r < 4; r++) inv[r] = 1.f / bpermf(4 * lg + r, l_);
#pragma unroll
  for (int cb = 0; cb < 4; cb++) {
#pragma unroll
    for (int r = 0; r < 4; r++) {
      out[(seq0 + q0 + 16 * w + 4 * lg + r) * (size_t)D_ + hc + cb * 16 + l15] =
          acc[cb][r] * inv[r];
    }
  }
}

extern "C" void kernel_launch(void* const* d_in, const int* in_sizes, int n_in,
                              void* d_out, int out_size, void* d_ws, size_t ws_size,
                              hipStream_t stream) {
  const float* X    = (const float*)d_in[0];
  const float* adj  = (const float*)d_in[1];
  const float* Wq   = (const float*)d_in[2];
  const float* bq   = (const float*)d_in[3];
  const float* Wk   = (const float*)d_in[4];
  const float* bk   = (const float*)d_in[5];
  const float* Wv   = (const float*)d_in[6];
  const float* bv   = (const float*)d_in[7];
  const float* beta = (const float*)d_in[8];
  float* out = (float*)d_out;

  // workspace (shorts): Xb | Wt3 | QKV | madjF ; VTg aliases Xb (dead after gemm)
  short* Xb    = (short*)d_ws;
  short* Wt3   = Xb + (size_t)(B_ * N_) * D_;
  short* QKV   = Wt3 + 3 * (size_t)D_ * D_;
  short* madjF = QKV + 3 * (size_t)(B_ * N_) * D_;
  short* VTg   = Xb;  // reuse: 8*12*64*1024 == 8*1024*768

  cvt_x_kernel<<<dim3((B_ * N_ * D_) / (256 * 8)), 256, 0, stream>>>(X, Xb);
  cvt_w_kernel<<<dim3(24, 24, 3), dim3(32, 8), 0, stream>>>(Wq, Wk, Wv, Wt3);
  madj_kernel<<<dim3(16, 16, 8), 256, 0, stream>>>(adj, beta, madjF);
  qkv_gemm_kernel<<<dim3(64, 6, 3), 256, 0, stream>>>(Xb, Wt3, bq, bk, bv, QKV);
  vT_kernel<<<dim3(16, 12, 8), 256, 0, stream>>>(QKV + 2 * (size_t)(B_ * N_) * D_, VTg);
  attn_kernel<<<dim3(1536), 256, 0, stream>>>(QKV, VTg, madjF, out);
}

// Round 6
// 127.129 us; speedup vs baseline: 1.8942x; 1.0322x over previous
//
#include <hip/hip_runtime.h>

#define B_ 8
#define N_ 1024
#define D_ 768
#define H_ 12
#define HD_ 64

#define LOG2E 1.4426950408889634f

typedef __attribute__((ext_vector_type(8))) short bf16x8;
typedef __attribute__((ext_vector_type(4))) short short4_t;
typedef __attribute__((ext_vector_type(4))) float f32x4;
typedef __attribute__((ext_vector_type(2))) unsigned int u32x2;
typedef unsigned int u32;

__device__ __forceinline__ short f2bf(float f) {
  union { float f; unsigned u; } v; v.f = f;
  unsigned u = v.u;
  unsigned r = u + 0x7fffu + ((u >> 16) & 1u);
  return (short)(r >> 16);
}
__device__ __forceinline__ float bf2f(short s) {
  union { unsigned u; float f; } v;
  v.u = ((unsigned)(unsigned short)s) << 16;
  return v.f;
}
__device__ __forceinline__ float bpermf(int srclane, float x) {
  union { float f; int i; } v; v.f = x;
  union { int i; float f; } r;
  r.i = __builtin_amdgcn_ds_bpermute(srclane * 4, v.i);
  return r.f;
}
__device__ __forceinline__ float max3f(float a, float b, float c) {
  return fmaxf(fmaxf(a, b), c);   // clang fuses to v_max3_f32
}
// packed bf16 pair: low = cvt(a), high = cvt(b); RNE rounding
__device__ __forceinline__ u32 cvtpk(float a, float b) {
  u32 r;
  asm("v_cvt_pk_bf16_f32 %0, %1, %2" : "=v"(r) : "v"(a), "v"(b));
  return r;
}

// direct global -> LDS DMA, 16B per lane. LDS dest = wave-uniform base + lane*16.
__device__ __forceinline__ void gload_lds16(const void* g, void* l) {
  __builtin_amdgcn_global_load_lds((const __attribute__((address_space(1))) u32*)g,
                                   (__attribute__((address_space(3))) u32*)l, 16, 0, 0);
}

// ---------------- conversion: X f32 -> bf16 ----------------
__global__ void cvt_x_kernel(const float* __restrict__ X, short* __restrict__ Xb) {
  int i = (blockIdx.x * 256 + threadIdx.x) * 8;
  float4 a = *(const float4*)(X + i);
  float4 b = *(const float4*)(X + i + 4);
  bf16x8 o;
  o[0] = f2bf(a.x); o[1] = f2bf(a.y); o[2] = f2bf(a.z); o[3] = f2bf(a.w);
  o[4] = f2bf(b.x); o[5] = f2bf(b.y); o[6] = f2bf(b.z); o[7] = f2bf(b.w);
  *(bf16x8*)(Xb + i) = o;
}

// ---------------- conversion: W f32 -> bf16, transposed (Wt[n][k] = W[k][n]) ----------------
__global__ void cvt_w_kernel(const float* __restrict__ Wq, const float* __restrict__ Wk,
                             const float* __restrict__ Wv, short* __restrict__ Wt3) {
  const float* W = blockIdx.z == 0 ? Wq : (blockIdx.z == 1 ? Wk : Wv);
  short* O = Wt3 + (size_t)blockIdx.z * D_ * D_;
  __shared__ float t[32][33];
  int n0 = blockIdx.x * 32, k0 = blockIdx.y * 32;
  int tx = threadIdx.x, ty = threadIdx.y;
#pragma unroll
  for (int j = 0; j < 4; j++)
    t[ty + 8 * j][tx] = W[(size_t)(k0 + ty + 8 * j) * D_ + n0 + tx];
  __syncthreads();
#pragma unroll
  for (int j = 0; j < 4; j++)
    O[(size_t)(n0 + ty + 8 * j) * D_ + k0 + tx] = f2bf(t[tx][ty + 8 * j]);
}

// ---------------- madjF: fused mask/beta/log2e, SWAPPED (S^T) fragment order, bf16 ----------
// attn thread t=(wm,lg,l15) slot (cb,r) needs madj(q = qt*64+16wm+l15, k = kt*64+16cb+4lg+r)
// stored at flat[((b*16+qt)*16+kt)*4096 + t*16 + cb*4 + r],  t = wm*64+lane
__global__ __launch_bounds__(256)
void madj_kernel(const float* __restrict__ adj, const float* __restrict__ beta_p,
                 short* __restrict__ madjF) {
  const int qt = blockIdx.x, kt = blockIdx.y, b = blockIdx.z;
  const int tid = threadIdx.x;
  const float b2 = beta_p[0] * LOG2E;
  const float MASKV = -9.0e15f * LOG2E;

  __shared__ float Lt[64][68];
  {
    const int row = tid >> 2, cs = (tid & 3) * 16;
    const float* ap = adj + ((size_t)b * N_ + qt * 64 + row) * (size_t)N_ + kt * 64 + cs;
#pragma unroll
    for (int j = 0; j < 4; j++)
      *(float4*)&Lt[row][cs + 4 * j] = *(const float4*)(ap + 4 * j);
  }
  __syncthreads();

  const int lane = tid & 63, w = tid >> 6;
  const int l15 = lane & 15, lg = lane >> 4;
  const int q = 16 * w + l15;
  short vals[16];
#pragma unroll
  for (int cb = 0; cb < 4; cb++) {
    float4 a4 = *(const float4*)&Lt[q][16 * cb + 4 * lg];
    float av[4] = {a4.x, a4.y, a4.z, a4.w};
#pragma unroll
    for (int r = 0; r < 4; r++) {
      float a = av[r];
      vals[cb * 4 + r] = f2bf((a > 0.f) ? b2 * a : MASKV);
    }
  }
  short* o = madjF + (((size_t)(b * 16 + qt) * 16 + kt) * 256 + tid) * 16;
  bf16x8 lo, hi;
#pragma unroll
  for (int j = 0; j < 8; j++) { lo[j] = vals[j]; hi[j] = vals[8 + j]; }
  *(bf16x8*)o = lo;
  *(bf16x8*)(o + 8) = hi;
}

// ---------------- QKV projection GEMM: C = X @ W + b (bf16 out, Q pre-scaled) ----------------
// double-buffered LDS, one barrier per K-step; z==2 epilogue writes V TRANSPOSED per head:
// VTg[((b*12+h)*64+d)][n] = V[b][n][h*64+d]
__global__ __launch_bounds__(256, 4)
void qkv_gemm_kernel(const short* __restrict__ Xb, const short* __restrict__ Wt3,
                     const float* __restrict__ bq, const float* __restrict__ bk,
                     const float* __restrict__ bv, short* __restrict__ QKV) {
  const int z = blockIdx.z;
  const short* Wt = Wt3 + (size_t)z * D_ * D_;
  const float* bias = z == 0 ? bq : (z == 1 ? bk : bv);
  short* C = QKV + (size_t)z * (B_ * N_) * D_;
  const float alpha = (z == 0) ? 0.125f * LOG2E : 1.0f;

  const int m0 = blockIdx.x * 128;
  const int n0 = blockIdx.y * 128;
  const int tid = threadIdx.x;
  const int lane = tid & 63;
  const int wid = tid >> 6;
  const int wr = (wid >> 1) * 64;
  const int wc = (wid & 1) * 64;
  const int l15 = lane & 15;
  const int lg = lane >> 4;

  __shared__ short At[2][128][32];
  __shared__ short Bt[2][128][32];

  f32x4 acc[4][4];
#pragma unroll
  for (int m = 0; m < 4; m++)
#pragma unroll
    for (int n = 0; n < 4; n++)
      acc[m][n] = (f32x4){0.f, 0.f, 0.f, 0.f};

  const int srow_l = lane >> 2;
  const int sc8 = (((lane & 3) ^ ((lane >> 2) & 3)) * 8);
  const short* ag = Xb + (size_t)(m0 + wid * 16 + srow_l) * D_ + sc8;
  const short* bg = Wt + (size_t)(n0 + wid * 16 + srow_l) * D_ + sc8;

  auto stage = [&](int bi, int k0) {
#pragma unroll
    for (int p = 0; p < 2; p++) {
      gload_lds16(ag + (size_t)(64 * p) * D_ + k0,
                  ((short*)At[bi]) + (size_t)(wid + 4 * p) * 512);
      gload_lds16(bg + (size_t)(64 * p) * D_ + k0,
                  ((short*)Bt[bi]) + (size_t)(wid + 4 * p) * 512);
    }
  };

  stage(0, 0);
  for (int k0 = 0; k0 < D_; k0 += 32) {
    const int cur = (k0 >> 5) & 1;
    __syncthreads();                       // drains vmcnt: buf[cur] ready
    if (k0 + 32 < D_) stage(cur ^ 1, k0 + 32);

    bf16x8 af[4], bfr[4];
#pragma unroll
    for (int m = 0; m < 4; m++) {
      const int row = wr + m * 16 + l15;
      af[m] = *(const bf16x8*)&At[cur][row][(lg ^ (l15 & 3)) * 8];
    }
#pragma unroll
    for (int n = 0; n < 4; n++) {
      const int row = wc + n * 16 + l15;
      bfr[n] = *(const bf16x8*)&Bt[cur][row][(lg ^ (l15 & 3)) * 8];
    }
#pragma unroll
    for (int m = 0; m < 4; m++)
#pragma unroll
      for (int n = 0; n < 4; n++)
        acc[m][n] = __builtin_amdgcn_mfma_f32_16x16x32_bf16(af[m], bfr[n], acc[m][n], 0, 0, 0);
  }

  if (z == 2) {
    // transposed per-head epilogue: 8B vector store over the r-quad
#pragma unroll
    for (int n = 0; n < 4; n++) {
      const int col = n0 + wc + n * 16 + l15;
      const float bval = bias[col];
      const int hh = col >> 6, dd = col & 63;
#pragma unroll
      for (int m = 0; m < 4; m++) {
        const int row = m0 + wr + m * 16 + 4 * lg;
        const int bb = row >> 10, nn = row & 1023;
        short4_t o;
#pragma unroll
        for (int r = 0; r < 4; r++) o[r] = f2bf(acc[m][n][r] + bval);
        *(short4_t*)&C[(((size_t)bb * H_ + hh) * HD_ + dd) * N_ + nn] = o;
      }
    }
  } else {
#pragma unroll
    for (int n = 0; n < 4; n++) {
      const int col = n0 + wc + n * 16 + l15;
      const float bval = bias[col];
#pragma unroll
      for (int m = 0; m < 4; m++) {
#pragma unroll
        for (int r = 0; r < 4; r++) {
          const int row = m0 + wr + m * 16 + 4 * lg + r;
          C[(size_t)row * D_ + col] = f2bf((acc[m][n][r] + bval) * alpha);
        }
      }
    }
  }
}

// ---------------- flash-style masked attention (8-wave, swapped-QK, dbuf) ------------------
__global__ __launch_bounds__(512, 4)
void attn_kernel(const short* __restrict__ QKV, const short* __restrict__ madjF,
                 float* __restrict__ out) {
  const short* Qb = QKV;
  const short* Kb = QKV + (size_t)(B_ * N_) * D_;
  const short* VTg = QKV + 2 * (size_t)(B_ * N_) * D_;   // per-head transposed V

  // 768 blocks = 8 XCD x 96; batch b pinned to XCD b
  const int wg = blockIdx.x;
  const int b = wg & 7;
  const int rem = wg >> 3;        // 0..95
  const int h = rem >> 3;         // 0..11
  const int qt = rem & 7;         // 0..7 (128-row q tiles)

  const int tid = threadIdx.x;
  const int lane = tid & 63;
  const int w = tid >> 6;         // wave 0..7: q rows [16w, 16w+16)
  const int l15 = lane & 15;
  const int lg = lane >> 4;

  const int q0 = qt * 128;
  const size_t seq0 = (size_t)b * N_;
  const int hc = h * HD_;

  __shared__ short Kt[2][64][64];    // row k', phys 16B-chunk p holds logical chunk p^(k'&7)
  __shared__ short VTt[2][64][64];   // row d, same swizzle over k-chunks
  __shared__ short Pt[8][16][64];    // per-wave; row q, 8B-chunk c at phys c^((q&7)<<1)

  bf16x8 qf[2];
  {
    const short* qp = Qb + (seq0 + q0 + 16 * w + l15) * (size_t)D_ + hc + 8 * lg;
    qf[0] = *(const bf16x8*)qp;
    qf[1] = *(const bf16x8*)(qp + 32);
  }

  f32x4 acc[4];
#pragma unroll
  for (int cb = 0; cb < 4; cb++) acc[cb] = (f32x4){0.f, 0.f, 0.f, 0.f};
  float m_ = -__builtin_inff();
  float l_ = 0.f;

  // staging: each wave stages 8 rows of K and 8 rows of V^T per tile
  const int srow = 8 * w + (lane >> 3);
  const int sc8 = ((lane & 7) ^ (lane >> 3)) * 8;
  const short* kg = Kb + (seq0 + srow) * (size_t)D_ + hc + sc8;
  const short* vg = VTg + ((size_t)(b * H_ + h) * HD_ + srow) * N_ + sc8;
  // madj fragment: 64-row madj q-tile qm, within-tile thread index (w&3)*64+lane
  const int qm = 2 * qt + (w >> 2);
  const short* mg = madjF + ((size_t)(b * 16 + qm) * 16) * 4096 + ((w & 3) * 64 + lane) * 16;

  const int sw2 = (l15 & 7) << 1;           // Pt chunk swizzle for row q=l15
  char* ptrow = (char*)&Pt[w][l15][0];      // write row (q = l15)

  auto stage = [&](int bi, int kt) {
    const int k0 = kt * 64;
    gload_lds16(kg + (size_t)k0 * D_, ((short*)Kt[bi]) + (size_t)w * 512);
    gload_lds16(vg + k0, ((short*)VTt[bi]) + (size_t)w * 512);
  };

  stage(0, 0);
  bf16x8 mlo = *(const bf16x8*)mg;
  bf16x8 mhi = *(const bf16x8*)(mg + 8);

  for (int kt = 0; kt < 16; kt++) {
    const int cur = kt & 1;
    __syncthreads();                        // drains vmcnt: buf[cur] staged, prev reads done
    if (kt < 15) stage(cur ^ 1, kt + 1);
    const int ktn = kt < 15 ? kt + 1 : 15;
    bf16x8 mlo2 = *(const bf16x8*)(mg + (size_t)ktn * 4096);
    bf16x8 mhi2 = *(const bf16x8*)(mg + (size_t)ktn * 4096 + 8);

    // S^T = K Q^T + madj  (lane holds S[q=l15][k=16cb+4lg+r], log2 units)
    f32x4 s[4];
#pragma unroll
    for (int cb = 0; cb < 4; cb++) {
      f32x4 c;
#pragma unroll
      for (int r = 0; r < 4; r++)
        c[r] = bf2f(cb < 2 ? mlo[(cb & 1) * 4 + r] : mhi[(cb & 1) * 4 + r]);
      const int swk = l15 & 7;
      bf16x8 kf0 = *(const bf16x8*)&Kt[cur][cb * 16 + l15][(lg ^ swk) * 8];
      bf16x8 kf1 = *(const bf16x8*)&Kt[cur][cb * 16 + l15][((lg + 4) ^ swk) * 8];
      c = __builtin_amdgcn_mfma_f32_16x16x32_bf16(kf0, qf[0], c, 0, 0, 0);
      s[cb] = __builtin_amdgcn_mfma_f32_16x16x32_bf16(kf1, qf[1], c, 0, 0, 0);
    }
    mlo = mlo2; mhi = mhi2;

    // lane-local row max (16 values, max3 tree) + reduce over lg (lanes ^16, ^32)
    float tm = max3f(max3f(s[0][0], s[0][1], s[0][2]),
                     max3f(s[0][3], s[1][0], s[1][1]),
                     max3f(s[1][2], s[1][3], s[2][0]));
    float tm2 = max3f(max3f(s[2][1], s[2][2], s[2][3]),
                      max3f(s[3][0], s[3][1], s[3][2]), s[3][3]);
    tm = fmaxf(tm, tm2);
    tm = fmaxf(tm, __shfl_xor(tm, 16));
    tm = fmaxf(tm, __shfl_xor(tm, 32));

    // defer-max: rescale only when the max actually grew past THR=8 (log2 units)
    if (!__all(tm <= m_ + 8.f)) {
      const float mnew = fmaxf(m_, tm);
      const float sc2 = __builtin_exp2f(m_ - mnew);
      m_ = mnew;
      l_ *= sc2;
      float scr[4];
#pragma unroll
      for (int r = 0; r < 4; r++) scr[r] = bpermf(4 * lg + r, sc2);
#pragma unroll
      for (int cb = 0; cb < 4; cb++)
#pragma unroll
        for (int r = 0; r < 4; r++) acc[cb][r] *= scr[r];
    }

    // P = exp2(s - m), packed bf16 pairs via v_cvt_pk_bf16_f32, row-sum in-register
    float ps = 0.f;
    u32 pk[8];
#pragma unroll
    for (int cb = 0; cb < 4; cb++) {
#pragma unroll
      for (int rp = 0; rp < 2; rp++) {
        const float p0 = __builtin_exp2f(s[cb][2 * rp] - m_);
        const float p1 = __builtin_exp2f(s[cb][2 * rp + 1] - m_);
        ps += p0 + p1;
        pk[cb * 2 + rp] = cvtpk(p0, p1);
      }
    }
    ps += __shfl_xor(ps, 16);
    ps += __shfl_xor(ps, 32);
    l_ += ps;

    // Pt write: chunk (4cb+lg) ^ sw2, 8B per cb
#pragma unroll
    for (int cb = 0; cb < 4; cb++) {
      u32x2 wv = {pk[2 * cb], pk[2 * cb + 1]};
      *(u32x2*)(ptrow + (((4 * cb + lg) ^ sw2) << 3)) = wv;
    }

    // O += P @ V   (Pt per-wave: no barrier)
#pragma unroll
    for (int ks = 0; ks < 2; ks++) {
      bf16x8 pa = *(const bf16x8*)(ptrow + ((((lg << 1) + 8 * ks) ^ sw2) << 3));
#pragma unroll
      for (int cb = 0; cb < 4; cb++) {
        const int row = cb * 16 + l15;
        bf16x8 vb = *(const bf16x8*)&VTt[cur][row][((lg + 4 * ks) ^ (row & 7)) * 8];
        acc[cb] = __builtin_amdgcn_mfma_f32_16x16x32_bf16(pa, vb, acc[cb], 0, 0, 0);
      }
    }
  }

  // bring 1/l from softmax layout (q=l15) to accumulator layout (q=4lg+r)
  float inv[4];
#pragma unroll
  for (int r = 0; r < 4; r++) inv[r] = 1.f / bpermf(4 * lg + r, l_);
#pragma unroll
  for (int cb = 0; cb < 4; cb++) {
#pragma unroll
    for (int r = 0; r < 4; r++) {
      out[(seq0 + q0 + 16 * w + 4 * lg + r) * (size_t)D_ + hc + cb * 16 + l15] =
          acc[cb][r] * inv[r];
    }
  }
}

extern "C" void kernel_launch(void* const* d_in, const int* in_sizes, int n_in,
                              void* d_out, int out_size, void* d_ws, size_t ws_size,
                              hipStream_t stream) {
  const float* X    = (const float*)d_in[0];
  const float* adj  = (const float*)d_in[1];
  const float* Wq   = (const float*)d_in[2];
  const float* bq   = (const float*)d_in[3];
  const float* Wk   = (const float*)d_in[4];
  const float* bk   = (const float*)d_in[5];
  const float* Wv   = (const float*)d_in[6];
  const float* bv   = (const float*)d_in[7];
  const float* beta = (const float*)d_in[8];
  float* out = (float*)d_out;

  // workspace (shorts): Xb | Wt3 | QKV | madjF  (V slab of QKV holds transposed V)
  short* Xb    = (short*)d_ws;
  short* Wt3   = Xb + (size_t)(B_ * N_) * D_;
  short* QKV   = Wt3 + 3 * (size_t)D_ * D_;
  short* madjF = QKV + 3 * (size_t)(B_ * N_) * D_;

  cvt_x_kernel<<<dim3((B_ * N_ * D_) / (256 * 8)), 256, 0, stream>>>(X, Xb);
  cvt_w_kernel<<<dim3(24, 24, 3), dim3(32, 8), 0, stream>>>(Wq, Wk, Wv, Wt3);
  madj_kernel<<<dim3(16, 16, 8), 256, 0, stream>>>(adj, beta, madjF);
  qkv_gemm_kernel<<<dim3(64, 6, 3), 256, 0, stream>>>(Xb, Wt3, bq, bk, bv, QKV);
  attn_kernel<<<dim3(768), 512, 0, stream>>>(QKV, madjF, out);
}